// Round 4
// baseline (585.929 us; speedup 1.0000x reference)
//
#include <hip/hip_runtime.h>

#define N_NODES 32000
typedef unsigned short u16;
typedef unsigned int u32;
typedef __attribute__((ext_vector_type(8))) short bf16x8;
typedef __attribute__((ext_vector_type(4))) float f32x4;

__device__ __forceinline__ float leakyf(float v) { return v >= 0.f ? v : 0.1f * v; }
__device__ __forceinline__ u16 f2bf(float f) {
    u32 u = __float_as_uint(f);
    return (u16)((u + 0x7FFFu + ((u >> 16) & 1u)) >> 16);
}
__device__ __forceinline__ float bf2f(u16 h) { return __uint_as_float(((u32)h) << 16); }
__device__ __forceinline__ float bf_lo(u32 u) { return __uint_as_float(u << 16); }
__device__ __forceinline__ float bf_hi(u32 u) { return __uint_as_float(u & 0xFFFF0000u); }
__device__ __forceinline__ u32 pack2(float a, float b) { return (u32)f2bf(a) | ((u32)f2bf(b) << 16); }

__device__ __forceinline__ void acc8(float* acc, uint4 v) {
    acc[0] += bf_lo(v.x); acc[1] += bf_hi(v.x);
    acc[2] += bf_lo(v.y); acc[3] += bf_hi(v.y);
    acc[4] += bf_lo(v.z); acc[5] += bf_hi(v.z);
    acc[6] += bf_lo(v.w); acc[7] += bf_hi(v.w);
}

__device__ __forceinline__ void gload16(const u16* g, u16* l) {
    __builtin_amdgcn_global_load_lds((const __attribute__((address_space(1))) void*)g,
                                     (__attribute__((address_space(3))) void*)l, 16, 0, 0);
}

// ---------------- CSR build ----------------
__global__ __launch_bounds__(256) void k_count(const int* __restrict__ dst, int* __restrict__ cnt, int E)
{
    int e = blockIdx.x * 256 + threadIdx.x;
    if (e < E) atomicAdd(&cnt[dst[e]], 1);
}

__global__ __launch_bounds__(1024) void k_scan(const int* __restrict__ cnt, int* __restrict__ rp, int n, int E)
{
    __shared__ int sh[1024];
    int t = threadIdx.x;
    int base = t * 32;
    int ls = 0;
#pragma unroll
    for (int i = 0; i < 32; ++i) { int idx = base + i; if (idx < n) ls += cnt[idx]; }
    sh[t] = ls;
    __syncthreads();
    for (int off = 1; off < 1024; off <<= 1) {
        int v = 0;
        if (t >= off) v = sh[t - off];
        __syncthreads();
        if (t >= off) sh[t] += v;
        __syncthreads();
    }
    int run = sh[t] - ls;
#pragma unroll
    for (int i = 0; i < 32; ++i) {
        int idx = base + i;
        if (idx < n) { rp[idx] = run; run += cnt[idx]; }
    }
    if (t == 0) rp[n] = E;
}

__global__ __launch_bounds__(256) void k_place(const int* __restrict__ src, const int* __restrict__ dst,
                                               const int* __restrict__ rp, int* __restrict__ cur,
                                               int* __restrict__ cs, int E)
{
    int e = blockIdx.x * 256 + threadIdx.x;
    if (e < E) {
        int d = dst[e];
        int p = rp[d] + atomicAdd(&cur[d], 1);
        cs[p] = src[e];
    }
}

// ---------------- fp32 -> bf16 ----------------
__global__ __launch_bounds__(256) void k_cvt(const float* __restrict__ in, u16* __restrict__ out)
{
    int i = blockIdx.x * 256 + threadIdx.x;
    float4 v = ((const float4*)in)[i];
    ushort4 o;
    o.x = f2bf(v.x); o.y = f2bf(v.y); o.z = f2bf(v.z); o.w = f2bf(v.w);
    ((ushort4*)out)[i] = o;
}

// ---------------- bf16 MFMA GEMM (m97 structure) ----------------
template <bool RELU, bool DEGB>
__global__ __launch_bounds__(256) void k_gemm_mfma(const u16* __restrict__ A, const u16* __restrict__ W,
                                                   const float* __restrict__ bias, const int* __restrict__ rp,
                                                   u16* __restrict__ C, int K, int OD)
{
    __shared__ u16 As[128 * 32];
    __shared__ u16 Bs[128 * 32];
    const int t = threadIdx.x;
    const int lane = t & 63;
    const int w = t >> 6;
    const int wr = w >> 1, wc = w & 1;
    const int bm = blockIdx.x * 128;
    const int bn = blockIdx.y * 128;

    const int c0 = w * 64 + lane;
    const int r0 = c0 >> 2, kc0 = (c0 & 3) * 8;
    const int c1 = c0 + 256;
    const int r1 = c1 >> 2, kc1 = (c1 & 3) * 8;
    const u16* gA0 = A + (size_t)(bm + r0) * K + kc0;
    const u16* gA1 = A + (size_t)(bm + r1) * K + kc1;
    const u16* gB0 = W + (size_t)(bn + r0) * K + kc0;
    const u16* gB1 = W + (size_t)(bn + r1) * K + kc1;
    u16* lA0 = As + w * 512;
    u16* lA1 = As + 2048 + w * 512;
    u16* lB0 = Bs + w * 512;
    u16* lB1 = Bs + 2048 + w * 512;

    f32x4 acc[4][4];
#pragma unroll
    for (int i = 0; i < 4; ++i)
#pragma unroll
        for (int j = 0; j < 4; ++j)
            acc[i][j] = (f32x4){0.f, 0.f, 0.f, 0.f};

    const int fr = lane & 15;
    const int ko = (lane >> 4) * 8;

    for (int k0 = 0; k0 < K; k0 += 32) {
        __syncthreads();
        gload16(gA0 + k0, lA0);
        gload16(gA1 + k0, lA1);
        gload16(gB0 + k0, lB0);
        gload16(gB1 + k0, lB1);
        asm volatile("s_waitcnt vmcnt(0)" ::: "memory");
        __syncthreads();
        bf16x8 af[4], bfv[4];
#pragma unroll
        for (int i = 0; i < 4; ++i)
            af[i] = *(const bf16x8*)&As[(wr * 64 + i * 16 + fr) * 32 + ko];
#pragma unroll
        for (int j = 0; j < 4; ++j)
            bfv[j] = *(const bf16x8*)&Bs[(wc * 64 + j * 16 + fr) * 32 + ko];
#pragma unroll
        for (int i = 0; i < 4; ++i)
#pragma unroll
            for (int j = 0; j < 4; ++j)
                acc[i][j] = __builtin_amdgcn_mfma_f32_16x16x32_bf16(af[i], bfv[j], acc[i][j], 0, 0, 0);
    }

    const int qr = (lane >> 4) * 4;
    float bcol[4];
#pragma unroll
    for (int j = 0; j < 4; ++j) bcol[j] = bias[bn + wc * 64 + j * 16 + fr];
#pragma unroll
    for (int i = 0; i < 4; ++i) {
#pragma unroll
        for (int r = 0; r < 4; ++r) {
            int row = bm + wr * 64 + i * 16 + qr + r;
            float bm_ = 1.f;
            if (DEGB) bm_ = (float)(rp[row + 1] - rp[row]) + 1.f;
#pragma unroll
            for (int j = 0; j < 4; ++j) {
                int col = bn + wc * 64 + j * 16 + fr;
                float o = acc[i][j][r] + bm_ * bcol[j];
                if (RELU) o = fmaxf(o, 0.f);
                C[(size_t)row * OD + col] = f2bf(o);
            }
        }
    }
}

// ---------------- aggregate + self (+relu), D=256: half-wave rows (16B/lane dwordx4) ----------------
template <bool RELU>
__global__ __launch_bounds__(256) void k_agg256(const u16* __restrict__ h, const int* __restrict__ rp,
                                                const int* __restrict__ cs, u16* __restrict__ out)
{
    const int lane = threadIdx.x & 63;
    const int n = blockIdx.x * 4 + (threadIdx.x >> 6);
    const int g = lane >> 5;        // half-wave group: edge parity
    const int c = lane & 31;        // 16B slot within the 512B row
    const u32* hb = (const u32*)h + c * 4;

    float acc[8];
    if (g == 0) {
        uint4 v = *(const uint4*)(hb + (size_t)n * 128);
        acc[0] = bf_lo(v.x); acc[1] = bf_hi(v.x);
        acc[2] = bf_lo(v.y); acc[3] = bf_hi(v.y);
        acc[4] = bf_lo(v.z); acc[5] = bf_hi(v.z);
        acc[6] = bf_lo(v.w); acc[7] = bf_hi(v.w);
    } else {
#pragma unroll
        for (int i = 0; i < 8; ++i) acc[i] = 0.f;
    }

    const int beg = rp[n], end = rp[n + 1];
    int e = beg;
    for (; e + 8 <= end; e += 8) {
        int i0 = cs[e + g];
        int i1 = cs[e + 2 + g];
        int i2 = cs[e + 4 + g];
        int i3 = cs[e + 6 + g];
        uint4 v0 = *(const uint4*)(hb + (size_t)i0 * 128);
        uint4 v1 = *(const uint4*)(hb + (size_t)i1 * 128);
        uint4 v2 = *(const uint4*)(hb + (size_t)i2 * 128);
        uint4 v3 = *(const uint4*)(hb + (size_t)i3 * 128);
        acc8(acc, v0); acc8(acc, v1); acc8(acc, v2); acc8(acc, v3);
    }
    for (; e + 4 <= end; e += 4) {
        int i0 = cs[e + g];
        int i1 = cs[e + 2 + g];
        uint4 v0 = *(const uint4*)(hb + (size_t)i0 * 128);
        uint4 v1 = *(const uint4*)(hb + (size_t)i1 * 128);
        acc8(acc, v0); acc8(acc, v1);
    }
    for (; e < end; e += 2) {
        if (e + g < end) {
            uint4 v = *(const uint4*)(hb + (size_t)cs[e + g] * 128);
            acc8(acc, v);
        }
    }
#pragma unroll
    for (int i = 0; i < 8; ++i) acc[i] += __shfl_xor(acc[i], 32);
    if (g == 0) {
        uint4 o;
        float a0 = acc[0], a1 = acc[1], a2 = acc[2], a3 = acc[3];
        float a4 = acc[4], a5 = acc[5], a6 = acc[6], a7 = acc[7];
        if (RELU) {
            a0 = fmaxf(a0, 0.f); a1 = fmaxf(a1, 0.f); a2 = fmaxf(a2, 0.f); a3 = fmaxf(a3, 0.f);
            a4 = fmaxf(a4, 0.f); a5 = fmaxf(a5, 0.f); a6 = fmaxf(a6, 0.f); a7 = fmaxf(a7, 0.f);
        }
        o.x = pack2(a0, a1); o.y = pack2(a2, a3); o.z = pack2(a4, a5); o.w = pack2(a6, a7);
        *(uint4*)((u32*)out + (size_t)n * 128 + c * 4) = o;
    }
}

// ---------------- aggregate + self (+relu), D=512: full-wave rows, unroll 8 ----------------
template <bool RELU>
__global__ __launch_bounds__(256) void k_agg512(const u16* __restrict__ h, const int* __restrict__ rp,
                                                const int* __restrict__ cs, u16* __restrict__ out)
{
    const int lane = threadIdx.x & 63;
    const int n = blockIdx.x * 4 + (threadIdx.x >> 6);
    const u32* hb = (const u32*)h + lane * 4;

    float acc[8];
    {
        uint4 v = *(const uint4*)(hb + (size_t)n * 256);
        acc[0] = bf_lo(v.x); acc[1] = bf_hi(v.x);
        acc[2] = bf_lo(v.y); acc[3] = bf_hi(v.y);
        acc[4] = bf_lo(v.z); acc[5] = bf_hi(v.z);
        acc[6] = bf_lo(v.w); acc[7] = bf_hi(v.w);
    }
    const int beg = rp[n], end = rp[n + 1];
    int e = beg;
    for (; e + 8 <= end; e += 8) {
        uint4 v[8];
#pragma unroll
        for (int u = 0; u < 8; ++u) v[u] = *(const uint4*)(hb + (size_t)cs[e + u] * 256);
#pragma unroll
        for (int u = 0; u < 8; ++u) acc8(acc, v[u]);
    }
    for (; e + 4 <= end; e += 4) {
        uint4 v[4];
#pragma unroll
        for (int u = 0; u < 4; ++u) v[u] = *(const uint4*)(hb + (size_t)cs[e + u] * 256);
#pragma unroll
        for (int u = 0; u < 4; ++u) acc8(acc, v[u]);
    }
    for (; e < end; ++e) {
        uint4 v = *(const uint4*)(hb + (size_t)cs[e] * 256);
        acc8(acc, v);
    }
    uint4 o;
    float a0 = acc[0], a1 = acc[1], a2 = acc[2], a3 = acc[3];
    float a4 = acc[4], a5 = acc[5], a6 = acc[6], a7 = acc[7];
    if (RELU) {
        a0 = fmaxf(a0, 0.f); a1 = fmaxf(a1, 0.f); a2 = fmaxf(a2, 0.f); a3 = fmaxf(a3, 0.f);
        a4 = fmaxf(a4, 0.f); a5 = fmaxf(a5, 0.f); a6 = fmaxf(a6, 0.f); a7 = fmaxf(a7, 0.f);
    }
    o.x = pack2(a0, a1); o.y = pack2(a2, a3); o.z = pack2(a4, a5); o.w = pack2(a6, a7);
    *(uint4*)((u32*)out + (size_t)n * 256 + lane * 4) = o;
}

// ---------------- batchnorm: u32 column loads, 256 rows/block, 125 blocks ----------------
template <int D>
__global__ __launch_bounds__(256) void k_bn_stats(const u16* __restrict__ h, float* __restrict__ sums)
{
    constexpr int SLOTS = D / 2;          // u32 per row (256 or 128)
    constexpr int NS = 256 / SLOTS;       // row substreams (1 or 2)
    const int t = threadIdx.x;
    const int s = t % SLOTS, j = t / SLOTS;
    const int r0 = blockIdx.x * 256;
    float sa = 0.f, sb = 0.f, qa = 0.f, qb = 0.f;
    for (int r = j; r < 256; r += NS) {
        u32 v = *((const u32*)(h + (size_t)(r0 + r) * D) + s);
        float a = bf_lo(v), b = bf_hi(v);
        sa += a; qa = fmaf(a, a, qa);
        sb += b; qb = fmaf(b, b, qb);
    }
    atomicAdd(&sums[2 * s], sa);
    atomicAdd(&sums[2 * s + 1], sb);
    atomicAdd(&sums[D + 2 * s], qa);
    atomicAdd(&sums[D + 2 * s + 1], qb);
}

__global__ __launch_bounds__(512) void k_bn_finalize(const float* __restrict__ sums, const float* __restrict__ gam,
                                                     const float* __restrict__ bet, float* __restrict__ ss, int D)
{
    int t = threadIdx.x;
    if (t < D) {
        const float invN = 1.f / (float)N_NODES;
        float mu  = sums[t] * invN;
        float var = sums[D + t] * invN - mu * mu;
        float rs  = rsqrtf(var + 1e-5f);
        float sc  = gam[t] * rs;
        ss[t]     = sc;
        ss[D + t] = bet[t] - mu * sc;
    }
}

__global__ __launch_bounds__(256) void k_bn_apply(u16* __restrict__ h, const float* __restrict__ ss, int D)
{
    int i = blockIdx.x * 256 + threadIdx.x;
    uint4 v = ((uint4*)h)[i];
    int c = (i * 8) & (D - 1);
    const float* sc = &ss[c];
    const float* sh = &ss[D + c];
    u32 r[4];
    u32 vv[4] = {v.x, v.y, v.z, v.w};
#pragma unroll
    for (int k = 0; k < 4; ++k) {
        float a = leakyf(fmaf(bf_lo(vv[k]), sc[2 * k], sh[2 * k]));
        float b = leakyf(fmaf(bf_hi(vv[k]), sc[2 * k + 1], sh[2 * k + 1]));
        r[k] = pack2(a, b);
    }
    ((uint4*)h)[i] = make_uint4(r[0], r[1], r[2], r[3]);
}

// ---------------- pool + head ----------------
__global__ __launch_bounds__(256) void k_pool(const u16* __restrict__ h, float* __restrict__ gp)
{
    int b = blockIdx.x, ch = blockIdx.y, t = threadIdx.x;
    int r0 = b * 2000 + ch * 250;
    float s = 0.f;
    for (int r = 0; r < 250; ++r) s += bf2f(h[(size_t)(r0 + r) * 256 + t]);
    atomicAdd(&gp[b * 256 + t], s);
}

__global__ __launch_bounds__(64) void k_final(const float* __restrict__ gp, const float* __restrict__ Wp,
                                              const float* __restrict__ bp, float* __restrict__ out)
{
    __shared__ float lg[32];
    int t = threadIdx.x;
    if (t < 32) {
        int b = t >> 1, c = t & 1;
        float s = 0.f;
        for (int k = 0; k < 256; ++k) s = fmaf(gp[b * 256 + k], Wp[c * 256 + k], s);
        float o = s * (1.f / 2000.f) + bp[c];
        out[b * 2 + c] = o;
        lg[t] = o;
    }
    __syncthreads();
    if (t < 16) out[32 + t] = (lg[t * 2 + 1] > lg[t * 2]) ? 1.f : 0.f;
}

extern "C" void kernel_launch(void* const* d_in, const int* in_sizes, int n_in,
                              void* d_out, int out_size, void* d_ws, size_t ws_size,
                              hipStream_t stream)
{
    const float* x   = (const float*)d_in[0];
    const int*   ei  = (const int*)d_in[1];
    const float* W1  = (const float*)d_in[2];
    const float* b1  = (const float*)d_in[3];
    const float* W2  = (const float*)d_in[4];
    const float* b2  = (const float*)d_in[5];
    const float* W3  = (const float*)d_in[6];
    const float* b3  = (const float*)d_in[7];
    const float* g1  = (const float*)d_in[8];
    const float* be1 = (const float*)d_in[9];
    const float* g2  = (const float*)d_in[10];
    const float* be2 = (const float*)d_in[11];
    const float* g3  = (const float*)d_in[12];
    const float* be3 = (const float*)d_in[13];
    const float* Wp  = (const float*)d_in[14];
    const float* bp  = (const float*)d_in[15];
    float* out = (float*)d_out;

    const int E = in_sizes[1] / 2;
    const int* src = ei;
    const int* dst = ei + E;

    char* ws = (char*)d_ws;
    size_t off = 0;
    auto alloc = [&](size_t bytes) -> void* {
        void* p = ws + off;
        off = (off + bytes + 255) & ~(size_t)255;
        return p;
    };
    u16*   bufA = (u16*)alloc((size_t)N_NODES * 512 * 2);
    u16*   bufB = (u16*)alloc((size_t)N_NODES * 512 * 2);
    u16*   xb   = (u16*)alloc((size_t)N_NODES * 256 * 2);
    u16*   w1b  = (u16*)alloc(512 * 256 * 2);
    u16*   w2b  = (u16*)alloc(512 * 512 * 2);
    u16*   w3b  = (u16*)alloc(256 * 512 * 2);
    int*   cs   = (int*)alloc((size_t)E * 4);
    int*   rp   = (int*)alloc((size_t)(N_NODES + 1) * 4);
    int*   cnt  = (int*)alloc((size_t)N_NODES * 4);
    int*   cur  = (int*)alloc((size_t)N_NODES * 4);
    float* sums = (float*)alloc(1024 * 4);
    float* ss   = (float*)alloc(1024 * 4);
    float* gp   = (float*)alloc(16 * 256 * 4);

    // CSR build
    hipMemsetAsync(cnt, 0, (size_t)N_NODES * 4, stream);
    hipMemsetAsync(cur, 0, (size_t)N_NODES * 4, stream);
    const int eb = (E + 255) / 256;
    k_count<<<eb, 256, 0, stream>>>(dst, cnt, E);
    k_scan<<<1, 1024, 0, stream>>>(cnt, rp, N_NODES, E);
    k_place<<<eb, 256, 0, stream>>>(src, dst, rp, cur, cs, E);

    // convert inputs/weights to bf16
    k_cvt<<<N_NODES * 256 / 4 / 256, 256, 0, stream>>>(x, xb);
    k_cvt<<<512 * 256 / 4 / 256, 256, 0, stream>>>(W1, w1b);
    k_cvt<<<512 * 512 / 4 / 256, 256, 0, stream>>>(W2, w2b);
    k_cvt<<<256 * 512 / 4 / 256, 256, 0, stream>>>(W3, w3b);

    // ---- layer 1 (linearity): s = x + sum_src x; z1 = relu(s@W1' + (deg+1)*b1) ----
    k_agg256<false><<<N_NODES / 4, 256, 0, stream>>>(xb, rp, cs, bufA);
    k_gemm_mfma<true, true><<<dim3(250, 4), 256, 0, stream>>>(bufA, w1b, b1, rp, bufB, 256, 512);
    hipMemsetAsync(sums, 0, 1024 * 4, stream);
    k_bn_stats<512><<<125, 256, 0, stream>>>(bufB, sums);
    k_bn_finalize<<<1, 512, 0, stream>>>(sums, g1, be1, ss, 512);
    k_bn_apply<<<N_NODES * 512 / 8 / 256, 256, 0, stream>>>(bufB, ss, 512);

    // ---- layer 2: GEMM then 512-wide agg+relu ----
    k_gemm_mfma<false, false><<<dim3(250, 4), 256, 0, stream>>>(bufB, w2b, b2, rp, bufA, 512, 512);
    k_agg512<true><<<N_NODES / 4, 256, 0, stream>>>(bufA, rp, cs, bufB);
    hipMemsetAsync(sums, 0, 1024 * 4, stream);
    k_bn_stats<512><<<125, 256, 0, stream>>>(bufB, sums);
    k_bn_finalize<<<1, 512, 0, stream>>>(sums, g2, be2, ss, 512);
    k_bn_apply<<<N_NODES * 512 / 8 / 256, 256, 0, stream>>>(bufB, ss, 512);

    // ---- layer 3: GEMM (512->256) then 256-wide agg+relu ----
    k_gemm_mfma<false, false><<<dim3(250, 2), 256, 0, stream>>>(bufB, w3b, b3, rp, bufA, 512, 256);
    k_agg256<true><<<N_NODES / 4, 256, 0, stream>>>(bufA, rp, cs, bufB);
    hipMemsetAsync(sums, 0, 1024 * 4, stream);
    k_bn_stats<256><<<125, 256, 0, stream>>>(bufB, sums);
    k_bn_finalize<<<1, 512, 0, stream>>>(sums, g3, be3, ss, 256);
    k_bn_apply<<<N_NODES * 256 / 8 / 256, 256, 0, stream>>>(bufB, ss, 256);

    // ---- pool + head ----
    hipMemsetAsync(gp, 0, 16 * 256 * 4, stream);
    k_pool<<<dim3(16, 8), 256, 0, stream>>>(bufB, gp);
    k_final<<<1, 64, 0, stream>>>(gp, Wp, bp, out);
}

// Round 5
// 479.656 us; speedup vs baseline: 1.2216x; 1.2216x over previous
//
#include <hip/hip_runtime.h>

#define N_NODES 32000
typedef unsigned short u16;
typedef unsigned int u32;
typedef unsigned char u8;
typedef __attribute__((ext_vector_type(8))) short bf16x8;
typedef __attribute__((ext_vector_type(4))) float f32x4;
typedef __attribute__((ext_vector_type(2))) float f32x2;

__device__ __forceinline__ float leakyf(float v) { return v >= 0.f ? v : 0.1f * v; }
__device__ __forceinline__ u16 f2bf(float f) {
    u32 u = __float_as_uint(f);
    return (u16)((u + 0x7FFFu + ((u >> 16) & 1u)) >> 16);
}
__device__ __forceinline__ float bf2f(u16 h) { return __uint_as_float(((u32)h) << 16); }
__device__ __forceinline__ float bf_lo(u32 u) { return __uint_as_float(u << 16); }
__device__ __forceinline__ float bf_hi(u32 u) { return __uint_as_float(u & 0xFFFF0000u); }
__device__ __forceinline__ u32 pack2(float a, float b) { return (u32)f2bf(a) | ((u32)f2bf(b) << 16); }

// fp8 e4m3 (OCP on gfx950) decode: 4 floats from one u32
__device__ __forceinline__ void dec4(float* acc, u32 w) {
    f32x2 lo = __builtin_amdgcn_cvt_pk_f32_fp8(w, false);
    f32x2 hi = __builtin_amdgcn_cvt_pk_f32_fp8(w, true);
    acc[0] += lo[0]; acc[1] += lo[1]; acc[2] += hi[0]; acc[3] += hi[1];
}
__device__ __forceinline__ void dec16(float* acc, uint4 v) {
    dec4(acc + 0, v.x); dec4(acc + 4, v.y); dec4(acc + 8, v.z); dec4(acc + 12, v.w);
}
__device__ __forceinline__ u8 f2fp8(float v) {
    return (u8)__builtin_amdgcn_cvt_pk_fp8_f32(v, v, 0, false);
}

__device__ __forceinline__ void gload16(const u16* g, u16* l) {
    __builtin_amdgcn_global_load_lds((const __attribute__((address_space(1))) void*)g,
                                     (__attribute__((address_space(3))) void*)l, 16, 0, 0);
}

// ---------------- CSR build ----------------
__global__ __launch_bounds__(256) void k_count(const int* __restrict__ dst, int* __restrict__ cnt, int E)
{
    int e = blockIdx.x * 256 + threadIdx.x;
    if (e < E) atomicAdd(&cnt[dst[e]], 1);
}

__global__ __launch_bounds__(1024) void k_scan(const int* __restrict__ cnt, int* __restrict__ rp, int n, int E)
{
    __shared__ int sh[1024];
    int t = threadIdx.x;
    int base = t * 32;
    int ls = 0;
#pragma unroll
    for (int i = 0; i < 32; ++i) { int idx = base + i; if (idx < n) ls += cnt[idx]; }
    sh[t] = ls;
    __syncthreads();
    for (int off = 1; off < 1024; off <<= 1) {
        int v = 0;
        if (t >= off) v = sh[t - off];
        __syncthreads();
        if (t >= off) sh[t] += v;
        __syncthreads();
    }
    int run = sh[t] - ls;
#pragma unroll
    for (int i = 0; i < 32; ++i) {
        int idx = base + i;
        if (idx < n) { rp[idx] = run; run += cnt[idx]; }
    }
    if (t == 0) rp[n] = E;
}

__global__ __launch_bounds__(256) void k_place(const int* __restrict__ src, const int* __restrict__ dst,
                                               const int* __restrict__ rp, int* __restrict__ cur,
                                               int* __restrict__ cs, int E)
{
    int e = blockIdx.x * 256 + threadIdx.x;
    if (e < E) {
        int d = dst[e];
        int p = rp[d] + atomicAdd(&cur[d], 1);
        cs[p] = src[e];
    }
}

// ---------------- conversions ----------------
__global__ __launch_bounds__(256) void k_cvt(const float* __restrict__ in, u16* __restrict__ out)
{
    int i = blockIdx.x * 256 + threadIdx.x;
    float4 v = ((const float4*)in)[i];
    ushort4 o;
    o.x = f2bf(v.x); o.y = f2bf(v.y); o.z = f2bf(v.z); o.w = f2bf(v.w);
    ((ushort4*)out)[i] = o;
}

__global__ __launch_bounds__(256) void k_cvt8(const float* __restrict__ in, u32* __restrict__ out)
{
    int i = blockIdx.x * 256 + threadIdx.x;
    float4 v = ((const float4*)in)[i];
    int p = __builtin_amdgcn_cvt_pk_fp8_f32(v.x, v.y, 0, false);
    p = __builtin_amdgcn_cvt_pk_fp8_f32(v.z, v.w, p, true);
    out[i] = (u32)p;
}

// ---------------- bf16 MFMA GEMM (m97 structure) ----------------
// C[m][o] = sum_k A[m][k]*W[o][k] + biasmul*bias[o]; biasmul=(deg+1) if DEGB; out bf16 or fp8.
template <bool RELU, bool DEGB, bool F8OUT>
__global__ __launch_bounds__(256) void k_gemm_mfma(const u16* __restrict__ A, const u16* __restrict__ W,
                                                   const float* __restrict__ bias, const int* __restrict__ rp,
                                                   void* __restrict__ Cv, int K, int OD)
{
    __shared__ u16 As[128 * 32];
    __shared__ u16 Bs[128 * 32];
    const int t = threadIdx.x;
    const int lane = t & 63;
    const int w = t >> 6;
    const int wr = w >> 1, wc = w & 1;
    const int bm = blockIdx.x * 128;
    const int bn = blockIdx.y * 128;

    const int c0 = w * 64 + lane;
    const int r0 = c0 >> 2, kc0 = (c0 & 3) * 8;
    const int c1 = c0 + 256;
    const int r1 = c1 >> 2, kc1 = (c1 & 3) * 8;
    const u16* gA0 = A + (size_t)(bm + r0) * K + kc0;
    const u16* gA1 = A + (size_t)(bm + r1) * K + kc1;
    const u16* gB0 = W + (size_t)(bn + r0) * K + kc0;
    const u16* gB1 = W + (size_t)(bn + r1) * K + kc1;
    u16* lA0 = As + w * 512;
    u16* lA1 = As + 2048 + w * 512;
    u16* lB0 = Bs + w * 512;
    u16* lB1 = Bs + 2048 + w * 512;

    f32x4 acc[4][4];
#pragma unroll
    for (int i = 0; i < 4; ++i)
#pragma unroll
        for (int j = 0; j < 4; ++j)
            acc[i][j] = (f32x4){0.f, 0.f, 0.f, 0.f};

    const int fr = lane & 15;
    const int ko = (lane >> 4) * 8;

    for (int k0 = 0; k0 < K; k0 += 32) {
        __syncthreads();
        gload16(gA0 + k0, lA0);
        gload16(gA1 + k0, lA1);
        gload16(gB0 + k0, lB0);
        gload16(gB1 + k0, lB1);
        asm volatile("s_waitcnt vmcnt(0)" ::: "memory");
        __syncthreads();
        bf16x8 af[4], bfv[4];
#pragma unroll
        for (int i = 0; i < 4; ++i)
            af[i] = *(const bf16x8*)&As[(wr * 64 + i * 16 + fr) * 32 + ko];
#pragma unroll
        for (int j = 0; j < 4; ++j)
            bfv[j] = *(const bf16x8*)&Bs[(wc * 64 + j * 16 + fr) * 32 + ko];
#pragma unroll
        for (int i = 0; i < 4; ++i)
#pragma unroll
            for (int j = 0; j < 4; ++j)
                acc[i][j] = __builtin_amdgcn_mfma_f32_16x16x32_bf16(af[i], bfv[j], acc[i][j], 0, 0, 0);
    }

    u16* C16 = (u16*)Cv;
    u8*  C8  = (u8*)Cv;
    const int qr = (lane >> 4) * 4;
    float bcol[4];
#pragma unroll
    for (int j = 0; j < 4; ++j) bcol[j] = bias[bn + wc * 64 + j * 16 + fr];
#pragma unroll
    for (int i = 0; i < 4; ++i) {
#pragma unroll
        for (int r = 0; r < 4; ++r) {
            int row = bm + wr * 64 + i * 16 + qr + r;
            float bm_ = 1.f;
            if (DEGB) bm_ = (float)(rp[row + 1] - rp[row]) + 1.f;
#pragma unroll
            for (int j = 0; j < 4; ++j) {
                int col = bn + wc * 64 + j * 16 + fr;
                float o = acc[i][j][r] + bm_ * bcol[j];
                if (RELU) o = fmaxf(o, 0.f);
                if (F8OUT) C8[(size_t)row * OD + col] = f2fp8(o);
                else       C16[(size_t)row * OD + col] = f2bf(o);
            }
        }
    }
}

// ---------------- fp8 gather+self(+relu), D=256: quarter-wave rows (16B = 16 fp8/lane) ----------------
template <bool RELU>
__global__ __launch_bounds__(256) void k_agg256_f8(const u8* __restrict__ h8, const int* __restrict__ rp,
                                                   const int* __restrict__ cs, u16* __restrict__ out)
{
    const int lane = threadIdx.x & 63;
    const int n = blockIdx.x * 4 + (threadIdx.x >> 6);
    const int g = lane >> 4;        // edge group 0..3
    const int c = lane & 15;        // 16B slot in 256B row
    const uint4* hb = (const uint4*)h8 + c;

    float acc[16];
#pragma unroll
    for (int i = 0; i < 16; ++i) acc[i] = 0.f;
    if (g == 0) dec16(acc, hb[(size_t)n * 16]);

    const int beg = rp[n], end = rp[n + 1];
    int e = beg;
    for (; e + 16 <= end; e += 16) {
        uint4 v0 = hb[(size_t)cs[e + g] * 16];
        uint4 v1 = hb[(size_t)cs[e + 4 + g] * 16];
        uint4 v2 = hb[(size_t)cs[e + 8 + g] * 16];
        uint4 v3 = hb[(size_t)cs[e + 12 + g] * 16];
        dec16(acc, v0); dec16(acc, v1); dec16(acc, v2); dec16(acc, v3);
    }
    for (; e + 4 <= end; e += 4) {
        uint4 v = hb[(size_t)cs[e + g] * 16];
        dec16(acc, v);
    }
    if (e + g < end) {
        uint4 v = hb[(size_t)cs[e + g] * 16];
        dec16(acc, v);
    }
#pragma unroll
    for (int i = 0; i < 16; ++i) acc[i] += __shfl_xor(acc[i], 16);
#pragma unroll
    for (int i = 0; i < 16; ++i) acc[i] += __shfl_xor(acc[i], 32);
    if (g == 0) {
        if (RELU) {
#pragma unroll
            for (int i = 0; i < 16; ++i) acc[i] = fmaxf(acc[i], 0.f);
        }
        uint4 o0, o1;
        o0.x = pack2(acc[0], acc[1]);  o0.y = pack2(acc[2], acc[3]);
        o0.z = pack2(acc[4], acc[5]);  o0.w = pack2(acc[6], acc[7]);
        o1.x = pack2(acc[8], acc[9]);  o1.y = pack2(acc[10], acc[11]);
        o1.z = pack2(acc[12], acc[13]); o1.w = pack2(acc[14], acc[15]);
        uint4* op = (uint4*)((u32*)out + (size_t)n * 128 + c * 8);
        op[0] = o0; op[1] = o1;
    }
}

// ---------------- fp8 gather+self(+relu), D=512: half-wave rows ----------------
template <bool RELU>
__global__ __launch_bounds__(256) void k_agg512_f8(const u8* __restrict__ h8, const int* __restrict__ rp,
                                                   const int* __restrict__ cs, u16* __restrict__ out)
{
    const int lane = threadIdx.x & 63;
    const int n = blockIdx.x * 4 + (threadIdx.x >> 6);
    const int g = lane >> 5;        // edge parity
    const int c = lane & 31;        // 16B slot in 512B row
    const uint4* hb = (const uint4*)h8 + c;

    float acc[16];
#pragma unroll
    for (int i = 0; i < 16; ++i) acc[i] = 0.f;
    if (g == 0) dec16(acc, hb[(size_t)n * 32]);

    const int beg = rp[n], end = rp[n + 1];
    int e = beg;
    for (; e + 8 <= end; e += 8) {
        uint4 v0 = hb[(size_t)cs[e + g] * 32];
        uint4 v1 = hb[(size_t)cs[e + 2 + g] * 32];
        uint4 v2 = hb[(size_t)cs[e + 4 + g] * 32];
        uint4 v3 = hb[(size_t)cs[e + 6 + g] * 32];
        dec16(acc, v0); dec16(acc, v1); dec16(acc, v2); dec16(acc, v3);
    }
    for (; e + 2 <= end; e += 2) {
        uint4 v = hb[(size_t)cs[e + g] * 32];
        dec16(acc, v);
    }
    if (e + g < end) {
        uint4 v = hb[(size_t)cs[e + g] * 32];
        dec16(acc, v);
    }
#pragma unroll
    for (int i = 0; i < 16; ++i) acc[i] += __shfl_xor(acc[i], 32);
    if (g == 0) {
        if (RELU) {
#pragma unroll
            for (int i = 0; i < 16; ++i) acc[i] = fmaxf(acc[i], 0.f);
        }
        uint4 o0, o1;
        o0.x = pack2(acc[0], acc[1]);  o0.y = pack2(acc[2], acc[3]);
        o0.z = pack2(acc[4], acc[5]);  o0.w = pack2(acc[6], acc[7]);
        o1.x = pack2(acc[8], acc[9]);  o1.y = pack2(acc[10], acc[11]);
        o1.z = pack2(acc[12], acc[13]); o1.w = pack2(acc[14], acc[15]);
        uint4* op = (uint4*)((u32*)out + (size_t)n * 256 + c * 8);
        op[0] = o0; op[1] = o1;
    }
}

// ---------------- batchnorm stats: 250 blocks x 128 rows, uint2 loads, LDS reduce ----------------
template <int D>
__global__ __launch_bounds__(256) void k_bn_stats(const u16* __restrict__ h, float* __restrict__ sums)
{
    constexpr int SLOTS = D / 4;      // uint2 slots per row: 128 (D=512) or 64 (D=256)
    constexpr int NS = 256 / SLOTS;   // substreams: 2 or 4
    const int t = threadIdx.x;
    const int s = t % SLOTS, j = t / SLOTS;
    const int r0 = blockIdx.x * 128;
    float a[4] = {0.f, 0.f, 0.f, 0.f}, q[4] = {0.f, 0.f, 0.f, 0.f};
    for (int r = j; r < 128; r += NS) {
        uint2 v = *((const uint2*)(h + (size_t)(r0 + r) * D) + s);
        float x0 = bf_lo(v.x), x1 = bf_hi(v.x), x2 = bf_lo(v.y), x3 = bf_hi(v.y);
        a[0] += x0; q[0] = fmaf(x0, x0, q[0]);
        a[1] += x1; q[1] = fmaf(x1, x1, q[1]);
        a[2] += x2; q[2] = fmaf(x2, x2, q[2]);
        a[3] += x3; q[3] = fmaf(x3, x3, q[3]);
    }
    __shared__ float red[8 * 256];
#pragma unroll
    for (int i = 0; i < 4; ++i) {
        red[i * 256 + t] = a[i];
        red[(4 + i) * 256 + t] = q[i];
    }
    __syncthreads();
    if (j == 0) {
        for (int k = 1; k < NS; ++k) {
            int o = k * SLOTS + s;
#pragma unroll
            for (int i = 0; i < 4; ++i) {
                a[i] += red[i * 256 + o];
                q[i] += red[(4 + i) * 256 + o];
            }
        }
#pragma unroll
        for (int i = 0; i < 4; ++i) {
            atomicAdd(&sums[4 * s + i], a[i]);
            atomicAdd(&sums[D + 4 * s + i], q[i]);
        }
    }
}

__global__ __launch_bounds__(512) void k_bn_finalize(const float* __restrict__ sums, const float* __restrict__ gam,
                                                     const float* __restrict__ bet, float* __restrict__ ss, int D)
{
    int t = threadIdx.x;
    if (t < D) {
        const float invN = 1.f / (float)N_NODES;
        float mu  = sums[t] * invN;
        float var = sums[D + t] * invN - mu * mu;
        float rs  = rsqrtf(var + 1e-5f);
        float sc  = gam[t] * rs;
        ss[t]     = sc;
        ss[D + t] = bet[t] - mu * sc;
    }
}

__global__ __launch_bounds__(256) void k_bn_apply(u16* __restrict__ h, const float* __restrict__ ss, int D)
{
    int i = blockIdx.x * 256 + threadIdx.x;
    uint4 v = ((uint4*)h)[i];
    int c = (i * 8) & (D - 1);
    const float* sc = &ss[c];
    const float* sh = &ss[D + c];
    u32 r[4];
    u32 vv[4] = {v.x, v.y, v.z, v.w};
#pragma unroll
    for (int k = 0; k < 4; ++k) {
        float a = leakyf(fmaf(bf_lo(vv[k]), sc[2 * k], sh[2 * k]));
        float b = leakyf(fmaf(bf_hi(vv[k]), sc[2 * k + 1], sh[2 * k + 1]));
        r[k] = pack2(a, b);
    }
    ((uint4*)h)[i] = make_uint4(r[0], r[1], r[2], r[3]);
}

// ---------------- pool + head ----------------
__global__ __launch_bounds__(256) void k_pool(const u16* __restrict__ h, float* __restrict__ gp)
{
    int b = blockIdx.x, ch = blockIdx.y, t = threadIdx.x;
    int s = t & 63, j = t >> 6;
    int r0 = b * 2000 + ch * 250;
    float a0 = 0.f, a1 = 0.f, a2 = 0.f, a3 = 0.f;
    for (int r = j; r < 250; r += 4) {
        uint2 v = *((const uint2*)(h + (size_t)(r0 + r) * 256) + s);
        a0 += bf_lo(v.x); a1 += bf_hi(v.x); a2 += bf_lo(v.y); a3 += bf_hi(v.y);
    }
    atomicAdd(&gp[b * 256 + s * 4 + 0], a0);
    atomicAdd(&gp[b * 256 + s * 4 + 1], a1);
    atomicAdd(&gp[b * 256 + s * 4 + 2], a2);
    atomicAdd(&gp[b * 256 + s * 4 + 3], a3);
}

__global__ __launch_bounds__(64) void k_final(const float* __restrict__ gp, const float* __restrict__ Wp,
                                              const float* __restrict__ bp, float* __restrict__ out)
{
    __shared__ float lg[32];
    int t = threadIdx.x;
    if (t < 32) {
        int b = t >> 1, c = t & 1;
        float s = 0.f;
        for (int k = 0; k < 256; ++k) s = fmaf(gp[b * 256 + k], Wp[c * 256 + k], s);
        float o = s * (1.f / 2000.f) + bp[c];
        out[b * 2 + c] = o;
        lg[t] = o;
    }
    __syncthreads();
    if (t < 16) out[32 + t] = (lg[t * 2 + 1] > lg[t * 2]) ? 1.f : 0.f;
}

extern "C" void kernel_launch(void* const* d_in, const int* in_sizes, int n_in,
                              void* d_out, int out_size, void* d_ws, size_t ws_size,
                              hipStream_t stream)
{
    const float* x   = (const float*)d_in[0];
    const int*   ei  = (const int*)d_in[1];
    const float* W1  = (const float*)d_in[2];
    const float* b1  = (const float*)d_in[3];
    const float* W2  = (const float*)d_in[4];
    const float* b2  = (const float*)d_in[5];
    const float* W3  = (const float*)d_in[6];
    const float* b3  = (const float*)d_in[7];
    const float* g1  = (const float*)d_in[8];
    const float* be1 = (const float*)d_in[9];
    const float* g2  = (const float*)d_in[10];
    const float* be2 = (const float*)d_in[11];
    const float* g3  = (const float*)d_in[12];
    const float* be3 = (const float*)d_in[13];
    const float* Wp  = (const float*)d_in[14];
    const float* bp  = (const float*)d_in[15];
    float* out = (float*)d_out;

    const int E = in_sizes[1] / 2;
    const int* src = ei;
    const int* dst = ei + E;

    char* ws = (char*)d_ws;
    size_t off = 0;
    auto alloc = [&](size_t bytes) -> void* {
        void* p = ws + off;
        off = (off + bytes + 255) & ~(size_t)255;
        return p;
    };
    u16*   bufA = (u16*)alloc((size_t)N_NODES * 512 * 2);
    u16*   bufB = (u16*)alloc((size_t)N_NODES * 512 * 2);
    u8*    buf8 = (u8*)alloc((size_t)N_NODES * 512);
    u8*    x8   = (u8*)alloc((size_t)N_NODES * 256);
    u16*   w1b  = (u16*)alloc(512 * 256 * 2);
    u16*   w2b  = (u16*)alloc(512 * 512 * 2);
    u16*   w3b  = (u16*)alloc(256 * 512 * 2);
    int*   cs   = (int*)alloc((size_t)E * 4);
    int*   rp   = (int*)alloc((size_t)(N_NODES + 1) * 4);
    int*   cnt  = (int*)alloc((size_t)N_NODES * 4);
    int*   cur  = (int*)alloc((size_t)N_NODES * 4);
    float* sums = (float*)alloc(1024 * 4);
    float* ss   = (float*)alloc(1024 * 4);
    float* gp   = (float*)alloc(16 * 256 * 4);

    // CSR build
    hipMemsetAsync(cnt, 0, (size_t)N_NODES * 4, stream);
    hipMemsetAsync(cur, 0, (size_t)N_NODES * 4, stream);
    const int eb = (E + 255) / 256;
    k_count<<<eb, 256, 0, stream>>>(dst, cnt, E);
    k_scan<<<1, 1024, 0, stream>>>(cnt, rp, N_NODES, E);
    k_place<<<eb, 256, 0, stream>>>(src, dst, rp, cur, cs, E);

    // conversions: x -> fp8 gather table; weights -> bf16
    k_cvt8<<<N_NODES * 256 / 4 / 256, 256, 0, stream>>>(x, (u32*)x8);
    k_cvt<<<512 * 256 / 4 / 256, 256, 0, stream>>>(W1, w1b);
    k_cvt<<<512 * 512 / 4 / 256, 256, 0, stream>>>(W2, w2b);
    k_cvt<<<256 * 512 / 4 / 256, 256, 0, stream>>>(W3, w3b);

    // ---- layer 1 (linearity): s = x + sum_src x (fp8 gather, bf16 out);
    //      h1 = relu(s@W1' + (deg+1)*b1) fused in GEMM ----
    k_agg256_f8<false><<<N_NODES / 4, 256, 0, stream>>>(x8, rp, cs, bufA);
    k_gemm_mfma<true, true, false><<<dim3(250, 4), 256, 0, stream>>>(bufA, w1b, b1, rp, bufB, 256, 512);
    hipMemsetAsync(sums, 0, 1024 * 4, stream);
    k_bn_stats<512><<<250, 256, 0, stream>>>(bufB, sums);
    k_bn_finalize<<<1, 512, 0, stream>>>(sums, g1, be1, ss, 512);
    k_bn_apply<<<N_NODES * 512 / 8 / 256, 256, 0, stream>>>(bufB, ss, 512);

    // ---- layer 2: GEMM (bf16 in, fp8 out) then 512-wide fp8 gather + relu ----
    k_gemm_mfma<false, false, true><<<dim3(250, 4), 256, 0, stream>>>(bufB, w2b, b2, rp, buf8, 512, 512);
    k_agg512_f8<true><<<N_NODES / 4, 256, 0, stream>>>(buf8, rp, cs, bufA);
    hipMemsetAsync(sums, 0, 1024 * 4, stream);
    k_bn_stats<512><<<250, 256, 0, stream>>>(bufA, sums);
    k_bn_finalize<<<1, 512, 0, stream>>>(sums, g2, be2, ss, 512);
    k_bn_apply<<<N_NODES * 512 / 8 / 256, 256, 0, stream>>>(bufA, ss, 512);

    // ---- layer 3: GEMM (512->256, fp8 out) then 256-wide fp8 gather + relu ----
    k_gemm_mfma<false, false, true><<<dim3(250, 2), 256, 0, stream>>>(bufA, w3b, b3, rp, buf8, 512, 256);
    k_agg256_f8<true><<<N_NODES / 4, 256, 0, stream>>>(buf8, rp, cs, bufB);
    hipMemsetAsync(sums, 0, 1024 * 4, stream);
    k_bn_stats<256><<<250, 256, 0, stream>>>(bufB, sums);
    k_bn_finalize<<<1, 512, 0, stream>>>(sums, g3, be3, ss, 256);
    k_bn_apply<<<N_NODES * 256 / 8 / 256, 256, 0, stream>>>(bufB, ss, 256);

    // ---- pool + head ----
    hipMemsetAsync(gp, 0, 16 * 256 * 4, stream);
    k_pool<<<dim3(16, 8), 256, 0, stream>>>(bufB, gp);
    k_final<<<1, 64, 0, stream>>>(gp, Wp, bp, out);
}

// Round 6
// 428.295 us; speedup vs baseline: 1.3681x; 1.1199x over previous
//
#include <hip/hip_runtime.h>

#define N_NODES 32000
typedef unsigned short u16;
typedef unsigned int u32;
typedef unsigned char u8;
typedef __attribute__((ext_vector_type(8))) short bf16x8;
typedef __attribute__((ext_vector_type(4))) float f32x4;
typedef __attribute__((ext_vector_type(2))) float f32x2;

__device__ __forceinline__ float leakyf(float v) { return v >= 0.f ? v : 0.1f * v; }
__device__ __forceinline__ u16 f2bf(float f) {
    u32 u = __float_as_uint(f);
    return (u16)((u + 0x7FFFu + ((u >> 16) & 1u)) >> 16);
}
__device__ __forceinline__ float bf2f(u16 h) { return __uint_as_float(((u32)h) << 16); }
__device__ __forceinline__ float bf_lo(u32 u) { return __uint_as_float(u << 16); }
__device__ __forceinline__ float bf_hi(u32 u) { return __uint_as_float(u & 0xFFFF0000u); }
__device__ __forceinline__ u32 pack2(float a, float b) { return (u32)f2bf(a) | ((u32)f2bf(b) << 16); }

// fp8 e4m3 (OCP on gfx950) decode: 4 floats from one u32
__device__ __forceinline__ void dec4(float* acc, u32 w) {
    f32x2 lo = __builtin_amdgcn_cvt_pk_f32_fp8(w, false);
    f32x2 hi = __builtin_amdgcn_cvt_pk_f32_fp8(w, true);
    acc[0] += lo[0]; acc[1] += lo[1]; acc[2] += hi[0]; acc[3] += hi[1];
}
__device__ __forceinline__ void dec16(float* acc, uint4 v) {
    dec4(acc + 0, v.x); dec4(acc + 4, v.y); dec4(acc + 8, v.z); dec4(acc + 12, v.w);
}
__device__ __forceinline__ u8 f2fp8(float v) {
    return (u8)__builtin_amdgcn_cvt_pk_fp8_f32(v, v, 0, false);
}

__device__ __forceinline__ void gload16(const u16* g, u16* l) {
    __builtin_amdgcn_global_load_lds((const __attribute__((address_space(1))) void*)g,
                                     (__attribute__((address_space(3))) void*)l, 16, 0, 0);
}

// ---------------- CSR build ----------------
__global__ __launch_bounds__(256) void k_count(const int* __restrict__ dst, int* __restrict__ cnt, int E)
{
    int e = blockIdx.x * 256 + threadIdx.x;
    if (e < E) atomicAdd(&cnt[dst[e]], 1);
}

// phase 1: per-block scan of 256 counts -> block-local exclusive prefix + block total
__global__ __launch_bounds__(256) void k_scan_blk(const int* __restrict__ cnt, int* __restrict__ rp,
                                                  int* __restrict__ bsum)
{
    __shared__ int sh[256];
    const int b = blockIdx.x, t = threadIdx.x;
    int v = cnt[b * 256 + t];
    sh[t] = v;
    __syncthreads();
    for (int off = 1; off < 256; off <<= 1) {
        int u = (t >= off) ? sh[t - off] : 0;
        __syncthreads();
        sh[t] += u;
        __syncthreads();
    }
    rp[b * 256 + t] = sh[t] - v;          // exclusive within block
    if (t == 255) bsum[b] = sh[255];      // block total
}

// phase 2: scan the 125 block totals (one small block)
__global__ __launch_bounds__(128) void k_scan_top(int* __restrict__ bsum, int nb)
{
    __shared__ int sh[128];
    const int t = threadIdx.x;
    int v = (t < nb) ? bsum[t] : 0;
    sh[t] = v;
    __syncthreads();
    for (int off = 1; off < 128; off <<= 1) {
        int u = (t >= off) ? sh[t - off] : 0;
        __syncthreads();
        sh[t] += u;
        __syncthreads();
    }
    if (t < nb) bsum[t] = sh[t] - v;      // exclusive block offsets
}

// phase 3: add block offsets; set rp[n]=E
__global__ __launch_bounds__(256) void k_scan_add(int* __restrict__ rp, const int* __restrict__ bsum,
                                                  int n, int E)
{
    int i = blockIdx.x * 256 + threadIdx.x;
    rp[i] += bsum[blockIdx.x];
    if (i == 0) rp[n] = E;
}

__global__ __launch_bounds__(256) void k_place(const int* __restrict__ src, const int* __restrict__ dst,
                                               const int* __restrict__ rp, int* __restrict__ cur,
                                               int* __restrict__ cs, int E)
{
    int e = blockIdx.x * 256 + threadIdx.x;
    if (e < E) {
        int d = dst[e];
        int p = rp[d] + atomicAdd(&cur[d], 1);
        cs[p] = src[e];
    }
}

// ---------------- conversions ----------------
__global__ __launch_bounds__(256) void k_cvt(const float* __restrict__ in, u16* __restrict__ out)
{
    int i = blockIdx.x * 256 + threadIdx.x;
    float4 v = ((const float4*)in)[i];
    ushort4 o;
    o.x = f2bf(v.x); o.y = f2bf(v.y); o.z = f2bf(v.z); o.w = f2bf(v.w);
    ((ushort4*)out)[i] = o;
}

__global__ __launch_bounds__(256) void k_cvt8(const float* __restrict__ in, u32* __restrict__ out)
{
    int i = blockIdx.x * 256 + threadIdx.x;
    float4 v = ((const float4*)in)[i];
    int p = __builtin_amdgcn_cvt_pk_fp8_f32(v.x, v.y, 0, false);
    p = __builtin_amdgcn_cvt_pk_fp8_f32(v.z, v.w, p, true);
    out[i] = (u32)p;
}

// ---------------- bf16 MFMA GEMM (m97 structure) ----------------
// C[m][o] = sum_k A[m][k]*W[o][k] + biasmul*bias[o]; biasmul=(deg+1) if DEGB; out bf16 or fp8.
template <bool RELU, bool DEGB, bool F8OUT>
__global__ __launch_bounds__(256) void k_gemm_mfma(const u16* __restrict__ A, const u16* __restrict__ W,
                                                   const float* __restrict__ bias, const int* __restrict__ rp,
                                                   void* __restrict__ Cv, int K, int OD)
{
    __shared__ u16 As[128 * 32];
    __shared__ u16 Bs[128 * 32];
    const int t = threadIdx.x;
    const int lane = t & 63;
    const int w = t >> 6;
    const int wr = w >> 1, wc = w & 1;
    const int bm = blockIdx.x * 128;
    const int bn = blockIdx.y * 128;

    const int c0 = w * 64 + lane;
    const int r0 = c0 >> 2, kc0 = (c0 & 3) * 8;
    const int c1 = c0 + 256;
    const int r1 = c1 >> 2, kc1 = (c1 & 3) * 8;
    const u16* gA0 = A + (size_t)(bm + r0) * K + kc0;
    const u16* gA1 = A + (size_t)(bm + r1) * K + kc1;
    const u16* gB0 = W + (size_t)(bn + r0) * K + kc0;
    const u16* gB1 = W + (size_t)(bn + r1) * K + kc1;
    u16* lA0 = As + w * 512;
    u16* lA1 = As + 2048 + w * 512;
    u16* lB0 = Bs + w * 512;
    u16* lB1 = Bs + 2048 + w * 512;

    f32x4 acc[4][4];
#pragma unroll
    for (int i = 0; i < 4; ++i)
#pragma unroll
        for (int j = 0; j < 4; ++j)
            acc[i][j] = (f32x4){0.f, 0.f, 0.f, 0.f};

    const int fr = lane & 15;
    const int ko = (lane >> 4) * 8;

    for (int k0 = 0; k0 < K; k0 += 32) {
        __syncthreads();
        gload16(gA0 + k0, lA0);
        gload16(gA1 + k0, lA1);
        gload16(gB0 + k0, lB0);
        gload16(gB1 + k0, lB1);
        asm volatile("s_waitcnt vmcnt(0)" ::: "memory");
        __syncthreads();
        bf16x8 af[4], bfv[4];
#pragma unroll
        for (int i = 0; i < 4; ++i)
            af[i] = *(const bf16x8*)&As[(wr * 64 + i * 16 + fr) * 32 + ko];
#pragma unroll
        for (int j = 0; j < 4; ++j)
            bfv[j] = *(const bf16x8*)&Bs[(wc * 64 + j * 16 + fr) * 32 + ko];
#pragma unroll
        for (int i = 0; i < 4; ++i)
#pragma unroll
            for (int j = 0; j < 4; ++j)
                acc[i][j] = __builtin_amdgcn_mfma_f32_16x16x32_bf16(af[i], bfv[j], acc[i][j], 0, 0, 0);
    }

    u16* C16 = (u16*)Cv;
    u8*  C8  = (u8*)Cv;
    const int qr = (lane >> 4) * 4;
    float bcol[4];
#pragma unroll
    for (int j = 0; j < 4; ++j) bcol[j] = bias[bn + wc * 64 + j * 16 + fr];
#pragma unroll
    for (int i = 0; i < 4; ++i) {
#pragma unroll
        for (int r = 0; r < 4; ++r) {
            int row = bm + wr * 64 + i * 16 + qr + r;
            float bm_ = 1.f;
            if (DEGB) bm_ = (float)(rp[row + 1] - rp[row]) + 1.f;
#pragma unroll
            for (int j = 0; j < 4; ++j) {
                int col = bn + wc * 64 + j * 16 + fr;
                float o = acc[i][j][r] + bm_ * bcol[j];
                if (RELU) o = fmaxf(o, 0.f);
                if (F8OUT) C8[(size_t)row * OD + col] = f2fp8(o);
                else       C16[(size_t)row * OD + col] = f2bf(o);
            }
        }
    }
}

// ---------------- fp8 gather+self(+relu), D=256: quarter-wave rows (16B = 16 fp8/lane) ----------------
template <bool RELU>
__global__ __launch_bounds__(256) void k_agg256_f8(const u8* __restrict__ h8, const int* __restrict__ rp,
                                                   const int* __restrict__ cs, u16* __restrict__ out)
{
    const int lane = threadIdx.x & 63;
    const int n = blockIdx.x * 4 + (threadIdx.x >> 6);
    const int g = lane >> 4;        // edge group 0..3
    const int c = lane & 15;        // 16B slot in 256B row
    const uint4* hb = (const uint4*)h8 + c;

    float acc[16];
#pragma unroll
    for (int i = 0; i < 16; ++i) acc[i] = 0.f;
    if (g == 0) dec16(acc, hb[(size_t)n * 16]);

    const int beg = rp[n], end = rp[n + 1];
    int e = beg;
    for (; e + 16 <= end; e += 16) {
        uint4 v0 = hb[(size_t)cs[e + g] * 16];
        uint4 v1 = hb[(size_t)cs[e + 4 + g] * 16];
        uint4 v2 = hb[(size_t)cs[e + 8 + g] * 16];
        uint4 v3 = hb[(size_t)cs[e + 12 + g] * 16];
        dec16(acc, v0); dec16(acc, v1); dec16(acc, v2); dec16(acc, v3);
    }
    for (; e + 4 <= end; e += 4) {
        uint4 v = hb[(size_t)cs[e + g] * 16];
        dec16(acc, v);
    }
    if (e + g < end) {
        uint4 v = hb[(size_t)cs[e + g] * 16];
        dec16(acc, v);
    }
#pragma unroll
    for (int i = 0; i < 16; ++i) acc[i] += __shfl_xor(acc[i], 16);
#pragma unroll
    for (int i = 0; i < 16; ++i) acc[i] += __shfl_xor(acc[i], 32);
    if (g == 0) {
        if (RELU) {
#pragma unroll
            for (int i = 0; i < 16; ++i) acc[i] = fmaxf(acc[i], 0.f);
        }
        uint4 o0, o1;
        o0.x = pack2(acc[0], acc[1]);  o0.y = pack2(acc[2], acc[3]);
        o0.z = pack2(acc[4], acc[5]);  o0.w = pack2(acc[6], acc[7]);
        o1.x = pack2(acc[8], acc[9]);  o1.y = pack2(acc[10], acc[11]);
        o1.z = pack2(acc[12], acc[13]); o1.w = pack2(acc[14], acc[15]);
        uint4* op = (uint4*)((u32*)out + (size_t)n * 128 + c * 8);
        op[0] = o0; op[1] = o1;
    }
}

// ---------------- fp8 gather+self(+relu), D=512: half-wave rows ----------------
template <bool RELU>
__global__ __launch_bounds__(256) void k_agg512_f8(const u8* __restrict__ h8, const int* __restrict__ rp,
                                                   const int* __restrict__ cs, u16* __restrict__ out)
{
    const int lane = threadIdx.x & 63;
    const int n = blockIdx.x * 4 + (threadIdx.x >> 6);
    const int g = lane >> 5;        // edge parity
    const int c = lane & 31;        // 16B slot in 512B row
    const uint4* hb = (const uint4*)h8 + c;

    float acc[16];
#pragma unroll
    for (int i = 0; i < 16; ++i) acc[i] = 0.f;
    if (g == 0) dec16(acc, hb[(size_t)n * 32]);

    const int beg = rp[n], end = rp[n + 1];
    int e = beg;
    for (; e + 8 <= end; e += 8) {
        uint4 v0 = hb[(size_t)cs[e + g] * 32];
        uint4 v1 = hb[(size_t)cs[e + 2 + g] * 32];
        uint4 v2 = hb[(size_t)cs[e + 4 + g] * 32];
        uint4 v3 = hb[(size_t)cs[e + 6 + g] * 32];
        dec16(acc, v0); dec16(acc, v1); dec16(acc, v2); dec16(acc, v3);
    }
    for (; e + 2 <= end; e += 2) {
        uint4 v = hb[(size_t)cs[e + g] * 32];
        dec16(acc, v);
    }
    if (e + g < end) {
        uint4 v = hb[(size_t)cs[e + g] * 32];
        dec16(acc, v);
    }
#pragma unroll
    for (int i = 0; i < 16; ++i) acc[i] += __shfl_xor(acc[i], 32);
    if (g == 0) {
        if (RELU) {
#pragma unroll
            for (int i = 0; i < 16; ++i) acc[i] = fmaxf(acc[i], 0.f);
        }
        uint4 o0, o1;
        o0.x = pack2(acc[0], acc[1]);  o0.y = pack2(acc[2], acc[3]);
        o0.z = pack2(acc[4], acc[5]);  o0.w = pack2(acc[6], acc[7]);
        o1.x = pack2(acc[8], acc[9]);  o1.y = pack2(acc[10], acc[11]);
        o1.z = pack2(acc[12], acc[13]); o1.w = pack2(acc[14], acc[15]);
        uint4* op = (uint4*)((u32*)out + (size_t)n * 256 + c * 8);
        op[0] = o0; op[1] = o1;
    }
}

// ---------------- batchnorm stats: 250 blocks x 128 rows, uint2 loads, LDS reduce ----------------
template <int D>
__global__ __launch_bounds__(256) void k_bn_stats(const u16* __restrict__ h, float* __restrict__ sums)
{
    constexpr int SLOTS = D / 4;      // uint2 slots per row: 128 (D=512) or 64 (D=256)
    constexpr int NS = 256 / SLOTS;   // substreams: 2 or 4
    const int t = threadIdx.x;
    const int s = t % SLOTS, j = t / SLOTS;
    const int r0 = blockIdx.x * 128;
    float a[4] = {0.f, 0.f, 0.f, 0.f}, q[4] = {0.f, 0.f, 0.f, 0.f};
    for (int r = j; r < 128; r += NS) {
        uint2 v = *((const uint2*)(h + (size_t)(r0 + r) * D) + s);
        float x0 = bf_lo(v.x), x1 = bf_hi(v.x), x2 = bf_lo(v.y), x3 = bf_hi(v.y);
        a[0] += x0; q[0] = fmaf(x0, x0, q[0]);
        a[1] += x1; q[1] = fmaf(x1, x1, q[1]);
        a[2] += x2; q[2] = fmaf(x2, x2, q[2]);
        a[3] += x3; q[3] = fmaf(x3, x3, q[3]);
    }
    __shared__ float red[8 * 256];
#pragma unroll
    for (int i = 0; i < 4; ++i) {
        red[i * 256 + t] = a[i];
        red[(4 + i) * 256 + t] = q[i];
    }
    __syncthreads();
    if (j == 0) {
        for (int k = 1; k < NS; ++k) {
            int o = k * SLOTS + s;
#pragma unroll
            for (int i = 0; i < 4; ++i) {
                a[i] += red[i * 256 + o];
                q[i] += red[(4 + i) * 256 + o];
            }
        }
#pragma unroll
        for (int i = 0; i < 4; ++i) {
            atomicAdd(&sums[4 * s + i], a[i]);
            atomicAdd(&sums[D + 4 * s + i], q[i]);
        }
    }
}

__global__ __launch_bounds__(512) void k_bn_finalize(const float* __restrict__ sums, const float* __restrict__ gam,
                                                     const float* __restrict__ bet, float* __restrict__ ss, int D)
{
    int t = threadIdx.x;
    if (t < D) {
        const float invN = 1.f / (float)N_NODES;
        float mu  = sums[t] * invN;
        float var = sums[D + t] * invN - mu * mu;
        float rs  = rsqrtf(var + 1e-5f);
        float sc  = gam[t] * rs;
        ss[t]     = sc;
        ss[D + t] = bet[t] - mu * sc;
    }
}

__global__ __launch_bounds__(256) void k_bn_apply(u16* __restrict__ h, const float* __restrict__ ss, int D)
{
    int i = blockIdx.x * 256 + threadIdx.x;
    uint4 v = ((uint4*)h)[i];
    int c = (i * 8) & (D - 1);
    const float* sc = &ss[c];
    const float* sh = &ss[D + c];
    u32 r[4];
    u32 vv[4] = {v.x, v.y, v.z, v.w};
#pragma unroll
    for (int k = 0; k < 4; ++k) {
        float a = leakyf(fmaf(bf_lo(vv[k]), sc[2 * k], sh[2 * k]));
        float b = leakyf(fmaf(bf_hi(vv[k]), sc[2 * k + 1], sh[2 * k + 1]));
        r[k] = pack2(a, b);
    }
    ((uint4*)h)[i] = make_uint4(r[0], r[1], r[2], r[3]);
}

// ---------------- pool + head ----------------
__global__ __launch_bounds__(256) void k_pool(const u16* __restrict__ h, float* __restrict__ gp)
{
    int b = blockIdx.x, ch = blockIdx.y, t = threadIdx.x;
    int s = t & 63, j = t >> 6;
    int r0 = b * 2000 + ch * 250;
    float a0 = 0.f, a1 = 0.f, a2 = 0.f, a3 = 0.f;
    for (int r = j; r < 250; r += 4) {
        uint2 v = *((const uint2*)(h + (size_t)(r0 + r) * 256) + s);
        a0 += bf_lo(v.x); a1 += bf_hi(v.x); a2 += bf_lo(v.y); a3 += bf_hi(v.y);
    }
    atomicAdd(&gp[b * 256 + s * 4 + 0], a0);
    atomicAdd(&gp[b * 256 + s * 4 + 1], a1);
    atomicAdd(&gp[b * 256 + s * 4 + 2], a2);
    atomicAdd(&gp[b * 256 + s * 4 + 3], a3);
}

__global__ __launch_bounds__(64) void k_final(const float* __restrict__ gp, const float* __restrict__ Wp,
                                              const float* __restrict__ bp, float* __restrict__ out)
{
    __shared__ float lg[32];
    int t = threadIdx.x;
    if (t < 32) {
        int b = t >> 1, c = t & 1;
        float s = 0.f;
        for (int k = 0; k < 256; ++k) s = fmaf(gp[b * 256 + k], Wp[c * 256 + k], s);
        float o = s * (1.f / 2000.f) + bp[c];
        out[b * 2 + c] = o;
        lg[t] = o;
    }
    __syncthreads();
    if (t < 16) out[32 + t] = (lg[t * 2 + 1] > lg[t * 2]) ? 1.f : 0.f;
}

extern "C" void kernel_launch(void* const* d_in, const int* in_sizes, int n_in,
                              void* d_out, int out_size, void* d_ws, size_t ws_size,
                              hipStream_t stream)
{
    const float* x   = (const float*)d_in[0];
    const int*   ei  = (const int*)d_in[1];
    const float* W1  = (const float*)d_in[2];
    const float* b1  = (const float*)d_in[3];
    const float* W2  = (const float*)d_in[4];
    const float* b2  = (const float*)d_in[5];
    const float* W3  = (const float*)d_in[6];
    const float* b3  = (const float*)d_in[7];
    const float* g1  = (const float*)d_in[8];
    const float* be1 = (const float*)d_in[9];
    const float* g2  = (const float*)d_in[10];
    const float* be2 = (const float*)d_in[11];
    const float* g3  = (const float*)d_in[12];
    const float* be3 = (const float*)d_in[13];
    const float* Wp  = (const float*)d_in[14];
    const float* bp  = (const float*)d_in[15];
    float* out = (float*)d_out;

    const int E = in_sizes[1] / 2;
    const int* src = ei;
    const int* dst = ei + E;

    char* ws = (char*)d_ws;
    size_t off = 0;
    auto alloc = [&](size_t bytes) -> void* {
        void* p = ws + off;
        off = (off + bytes + 255) & ~(size_t)255;
        return p;
    };
    u16*   bufA = (u16*)alloc((size_t)N_NODES * 512 * 2);
    u16*   bufB = (u16*)alloc((size_t)N_NODES * 512 * 2);
    u8*    buf8 = (u8*)alloc((size_t)N_NODES * 512);
    u8*    x8   = (u8*)alloc((size_t)N_NODES * 256);
    u16*   w1b  = (u16*)alloc(512 * 256 * 2);
    u16*   w2b  = (u16*)alloc(512 * 512 * 2);
    u16*   w3b  = (u16*)alloc(256 * 512 * 2);
    int*   cs   = (int*)alloc((size_t)E * 4);
    int*   rp   = (int*)alloc((size_t)(N_NODES + 1) * 4);
    int*   cnt  = (int*)alloc((size_t)N_NODES * 4);
    int*   cur  = (int*)alloc((size_t)N_NODES * 4);
    int*   bsum = (int*)alloc(256 * 4);
    float* sums = (float*)alloc(1024 * 4);
    float* ss   = (float*)alloc(1024 * 4);
    float* gp   = (float*)alloc(16 * 256 * 4);

    // CSR build (parallel 3-phase scan)
    hipMemsetAsync(cnt, 0, (size_t)N_NODES * 4, stream);
    hipMemsetAsync(cur, 0, (size_t)N_NODES * 4, stream);
    const int eb = (E + 255) / 256;
    const int nb = N_NODES / 256;   // 125
    k_count<<<eb, 256, 0, stream>>>(dst, cnt, E);
    k_scan_blk<<<nb, 256, 0, stream>>>(cnt, rp, bsum);
    k_scan_top<<<1, 128, 0, stream>>>(bsum, nb);
    k_scan_add<<<nb, 256, 0, stream>>>(rp, bsum, N_NODES, E);
    k_place<<<eb, 256, 0, stream>>>(src, dst, rp, cur, cs, E);

    // conversions: x -> fp8 gather table; weights -> bf16
    k_cvt8<<<N_NODES * 256 / 4 / 256, 256, 0, stream>>>(x, (u32*)x8);
    k_cvt<<<512 * 256 / 4 / 256, 256, 0, stream>>>(W1, w1b);
    k_cvt<<<512 * 512 / 4 / 256, 256, 0, stream>>>(W2, w2b);
    k_cvt<<<256 * 512 / 4 / 256, 256, 0, stream>>>(W3, w3b);

    // ---- layer 1 (linearity): s = x + sum_src x (fp8 gather, bf16 out);
    //      h1 = relu(s@W1' + (deg+1)*b1) fused in GEMM ----
    k_agg256_f8<false><<<N_NODES / 4, 256, 0, stream>>>(x8, rp, cs, bufA);
    k_gemm_mfma<true, true, false><<<dim3(250, 4), 256, 0, stream>>>(bufA, w1b, b1, rp, bufB, 256, 512);
    hipMemsetAsync(sums, 0, 1024 * 4, stream);
    k_bn_stats<512><<<250, 256, 0, stream>>>(bufB, sums);
    k_bn_finalize<<<1, 512, 0, stream>>>(sums, g1, be1, ss, 512);
    k_bn_apply<<<N_NODES * 512 / 8 / 256, 256, 0, stream>>>(bufB, ss, 512);

    // ---- layer 2: GEMM (bf16 in, fp8 out) then 512-wide fp8 gather + relu ----
    k_gemm_mfma<false, false, true><<<dim3(250, 4), 256, 0, stream>>>(bufB, w2b, b2, rp, buf8, 512, 512);
    k_agg512_f8<true><<<N_NODES / 4, 256, 0, stream>>>(buf8, rp, cs, bufA);
    hipMemsetAsync(sums, 0, 1024 * 4, stream);
    k_bn_stats<512><<<250, 256, 0, stream>>>(bufA, sums);
    k_bn_finalize<<<1, 512, 0, stream>>>(sums, g2, be2, ss, 512);
    k_bn_apply<<<N_NODES * 512 / 8 / 256, 256, 0, stream>>>(bufA, ss, 512);

    // ---- layer 3: GEMM (512->256, fp8 out) then 256-wide fp8 gather + relu ----
    k_gemm_mfma<false, false, true><<<dim3(250, 2), 256, 0, stream>>>(bufA, w3b, b3, rp, buf8, 512, 256);
    k_agg256_f8<true><<<N_NODES / 4, 256, 0, stream>>>(buf8, rp, cs, bufB);
    hipMemsetAsync(sums, 0, 1024 * 4, stream);
    k_bn_stats<256><<<250, 256, 0, stream>>>(bufB, sums);
    k_bn_finalize<<<1, 512, 0, stream>>>(sums, g3, be3, ss, 256);
    k_bn_apply<<<N_NODES * 256 / 8 / 256, 256, 0, stream>>>(bufB, ss, 256);

    // ---- pool + head ----
    hipMemsetAsync(gp, 0, 16 * 256 * 4, stream);
    k_pool<<<dim3(16, 8), 256, 0, stream>>>(bufB, gp);
    k_final<<<1, 64, 0, stream>>>(gp, Wp, bp, out);
}